// Round 6
// baseline (1210.479 us; speedup 1.0000x reference)
//
#include <hip/hip_runtime.h>

#define H 64
#define N_STAY 200000
#define N_PAT  100000
#define N_EDGE 1000000
#define NB_STAY 3125   // 200000/64
#define NB_PAT  1563   // ceil(100000/64)

typedef unsigned short ushort_t;
typedef __attribute__((ext_vector_type(8))) short bf16x8;
typedef __attribute__((ext_vector_type(4))) float f32x4;

__device__ __forceinline__ float wave_sum(float v) {
  #pragma unroll
  for (int off = 32; off > 0; off >>= 1) v += __shfl_xor(v, off);
  return v;
}

__device__ __forceinline__ float bf2f(ushort_t u) {
  union { unsigned int i; float f; } c;
  c.i = ((unsigned int)u) << 16;
  return c.f;
}
__device__ __forceinline__ unsigned int f2bf_bits(float f) {
  union { float v; unsigned int i; } c; c.v = f;
  unsigned int r = c.i + 0x7fffu + ((c.i >> 16) & 1u);  // RNE
  return r >> 16;
}
__device__ __forceinline__ unsigned int pack2(float lo, float hi) {
  return f2bf_bits(lo) | (f2bf_bits(hi) << 16);
}
__device__ __forceinline__ void unpack8(uint4 q, float* f) {
  union { unsigned int i; float v; } c;
  c.i = q.x << 16;          f[0] = c.v;
  c.i = q.x & 0xffff0000u;  f[1] = c.v;
  c.i = q.y << 16;          f[2] = c.v;
  c.i = q.y & 0xffff0000u;  f[3] = c.v;
  c.i = q.z << 16;          f[4] = c.v;
  c.i = q.z & 0xffff0000u;  f[5] = c.v;
  c.i = q.w << 16;          f[6] = c.v;
  c.i = q.w & 0xffff0000u;  f[7] = c.v;
}
__device__ __forceinline__ bf16x8 ld_frag(const ushort_t* p) {
  union { uint4 u; bf16x8 v; } c;
  c.u = *(const uint4*)p;
  return c.v;
}

// ---------------- CSR build: coarse bin (dst>>6) + per-bucket fine sort ------

// coarse histogram, 3 lists in one dispatch
__global__ __launch_bounds__(256)
void bhist3_kernel(const int* __restrict__ d1, const int* __restrict__ d2,
                   const int* __restrict__ d3,
                   int* __restrict__ h1, int* __restrict__ h2, int* __restrict__ h3,
                   int eb) {
  int which = blockIdx.x / eb;
  int e = (blockIdx.x % eb) * 256 + threadIdx.x;
  if (e >= N_EDGE) return;
  if (which == 0)      atomicAdd(&h1[d1[e] >> 6], 1);
  else if (which == 1) atomicAdd(&h2[d2[e] >> 6], 1);
  else                 atomicAdd(&h3[d3[e] >> 6], 1);
}

// single-block exclusive scan, n <= 4096; writes off[0..n] and cur[0..n-1]
__global__ __launch_bounds__(256)
void scan_one(const int* __restrict__ in, int n, int* __restrict__ off,
              int* __restrict__ cur, int total) {
  int tid = threadIdx.x;
  int base = tid * 16;
  int vals[16]; int s = 0;
  #pragma unroll
  for (int i = 0; i < 16; ++i) {
    int idx = base + i;
    vals[i] = (idx < n) ? in[idx] : 0;
    s += vals[i];
  }
  int lane = tid & 63, w = tid >> 6;
  int incl = s;
  #pragma unroll
  for (int o = 1; o < 64; o <<= 1) {
    int t = __shfl_up(incl, o);
    if (lane >= o) incl += t;
  }
  __shared__ int wtot[4];
  if (lane == 63) wtot[w] = incl;
  __syncthreads();
  int wbase = 0;
  for (int i = 0; i < w; ++i) wbase += wtot[i];
  int run = wbase + incl - s;
  #pragma unroll
  for (int i = 0; i < 16; ++i) {
    int idx = base + i;
    if (idx < n) { off[idx] = run; cur[idx] = run; run += vals[i]; }
  }
  if (tid == 0) off[n] = total;
}

// coarse scatter: packed value = src | ((dst&63)<<18). Cursor lines stay L2-hot
// (monotone per-bucket) so 64B lines fill before eviction -> ~no write-allocate
// amplification.
__global__ __launch_bounds__(256)
void scatter3_kernel(const int* __restrict__ s1, const int* __restrict__ d1,
                     const int* __restrict__ s2, const int* __restrict__ d2,
                     const int* __restrict__ s3, const int* __restrict__ d3,
                     int* __restrict__ c1, int* __restrict__ c2, int* __restrict__ c3,
                     int* __restrict__ v1, int* __restrict__ v2, int* __restrict__ v3,
                     int eb) {
  int which = blockIdx.x / eb;
  int e = (blockIdx.x % eb) * 256 + threadIdx.x;
  if (e >= N_EDGE) return;
  const int* sp = (which == 0) ? s1 : (which == 1) ? s2 : s3;
  const int* dp = (which == 0) ? d1 : (which == 1) ? d2 : d3;
  int* cp = (which == 0) ? c1 : (which == 1) ? c2 : c3;
  int* vp = (which == 0) ? v1 : (which == 1) ? v2 : v3;
  int d = dp[e], s = sp[e];
  int pos = atomicAdd(&cp[d >> 6], 1);
  vp[pos] = s | ((d & 63) << 18);
}

// per-bucket fine sort: LDS hist(64) + wave scan + LDS-cursor placement.
// Emits dst-sorted csr (src only) and per-node off[]. 3 lists in one dispatch.
__global__ __launch_bounds__(256)
void fine3_kernel(const int* __restrict__ v1, const int* __restrict__ bo1,
                  const int* __restrict__ v2, const int* __restrict__ bo2,
                  const int* __restrict__ v3, const int* __restrict__ bo3,
                  int* __restrict__ csr1, int* __restrict__ off1,
                  int* __restrict__ csr2, int* __restrict__ off2,
                  int* __restrict__ csr3, int* __restrict__ off3) {
  int b = blockIdx.x;
  const int* v; const int* bo; int* csr; int* off; int N; int lb;
  if (b < NB_PAT)                { v = v1; bo = bo1; csr = csr1; off = off1; N = N_PAT;  lb = b; }
  else if (b < NB_PAT + NB_STAY) { v = v2; bo = bo2; csr = csr2; off = off2; N = N_STAY; lb = b - NB_PAT; }
  else                           { v = v3; bo = bo3; csr = csr3; off = off3; N = N_STAY; lb = b - NB_PAT - NB_STAY; }
  const int base = bo[lb], end = bo[lb + 1];
  __shared__ int lhist[64];
  __shared__ int lcur[64];
  if (threadIdx.x < 64) lhist[threadIdx.x] = 0;
  __syncthreads();
  for (int i = base + threadIdx.x; i < end; i += 256)
    atomicAdd(&lhist[(v[i] >> 18) & 63], 1);
  __syncthreads();
  if (threadIdx.x < 64) {
    int lane = threadIdx.x;
    int x = lhist[lane];
    int incl = x;
    #pragma unroll
    for (int o = 1; o < 64; o <<= 1) {
      int t = __shfl_up(incl, o);
      if (lane >= o) incl += t;
    }
    int excl = incl - x;
    lcur[lane] = base + excl;
    int node = lb * 64 + lane;
    if (node < N) off[node] = base + excl;
  }
  __syncthreads();
  for (int i = base + threadIdx.x; i < end; i += 256) {
    int val = v[i];
    int pos = atomicAdd(&lcur[(val >> 18) & 63], 1);
    csr[pos] = val & 0x3FFFF;
  }
  if (b == 0 && threadIdx.x == 0) {
    off1[N_PAT] = N_EDGE;
    off2[N_STAY] = N_EDGE;
    off3[N_STAY] = N_EDGE;
  }
}

// ---------------- weight preconversion to MFMA B-fragments (hi+lo bf16) -----

template<int K>
__global__ __launch_bounds__(256)
void precvt_kernel(const float* __restrict__ src, ushort_t* __restrict__ dst, int nmat) {
  const int KS = K / 32;
  const int FU = KS * 4;
  const int PLANE = FU * 64 * 8;
  int fu = blockIdx.x * 4 + (threadIdx.x >> 6);
  int lane = threadIdx.x & 63;
  int mi = fu / FU;
  if (mi >= nmat) return;
  int fid = fu % FU;
  int ntile = fid / KS;
  int kstep = fid % KS;
  int q = lane >> 4, n = ntile * 16 + (lane & 15);
  const float* W = src + (size_t)mi * K * H;
  union { ushort_t s[8]; uint4 u; } hi, lo;
  #pragma unroll
  for (int j = 0; j < 8; ++j) {
    float v = W[(size_t)(kstep * 32 + q * 8 + j) * H + n];
    unsigned hb = f2bf_bits(v);
    hi.s[j] = (ushort_t)hb;
    lo.s[j] = (ushort_t)f2bf_bits(v - bf2f((ushort_t)hb));
  }
  ushort_t* base = dst + (size_t)mi * 2 * PLANE + ((size_t)fid * 64 + lane) * 8;
  *(uint4*)base = hi.u;
  *(uint4*)(base + PLANE) = lo.u;
}

// ---------------- aggregation: wave per dst node, 8 edges x 8 lanes ----------

__global__ __launch_bounds__(256)
void agg_kernel(const ushort_t* __restrict__ x, const int* __restrict__ off,
                const int* __restrict__ csr, ushort_t* __restrict__ agg, int N) {
  const int node = (int)((blockIdx.x * 256 + threadIdx.x) >> 6);
  const int lane = threadIdx.x & 63;
  if (node >= N) return;
  const int o0 = off[node], o1 = off[node + 1];
  const int slot = lane >> 3;
  const int fg = lane & 7;
  float acc[8] = {0, 0, 0, 0, 0, 0, 0, 0};
  for (int t = o0 + slot; t < o1; t += 8) {
    int s = csr[t];
    uint4 q = *(const uint4*)(x + (size_t)s * H + fg * 8);
    float f[8];
    unpack8(q, f);
    #pragma unroll
    for (int j = 0; j < 8; ++j) acc[j] += f[j];
  }
  #pragma unroll
  for (int o = 8; o < 64; o <<= 1)
    #pragma unroll
    for (int j = 0; j < 8; ++j) acc[j] += __shfl_xor(acc[j], o);
  if (slot == 0) {
    const float inv = 1.0f / fmaxf((float)(o1 - o0), 1.0f);
    uint4 q;
    q.x = pack2(acc[0] * inv, acc[1] * inv);
    q.y = pack2(acc[2] * inv, acc[3] * inv);
    q.z = pack2(acc[4] * inv, acc[5] * inv);
    q.w = pack2(acc[6] * inv, acc[7] * inv);
    *(uint4*)(agg + (size_t)node * H + fg * 8) = q;
  }
}

// ---------------- MFMA dense kernels ----------------------------------------

#define MFMA16(a, b, c) __builtin_amdgcn_mfma_f32_16x16x32_bf16((a), (b), (c), 0, 0, 0)

template<int K>
__global__ __launch_bounds__(256)
void proj_mfma(const float* __restrict__ x, const ushort_t* __restrict__ fw,
               const float* __restrict__ b, ushort_t* __restrict__ y, int N) {
  const int KS = K / 32;
  const int PLANE = KS * 4 * 64 * 8;
  const int wid = threadIdx.x >> 6, lane = threadIdx.x & 63;
  const int r0 = blockIdx.x * 64 + wid * 16;
  if (r0 >= N) return;
  const int m = lane & 15, q = lane >> 4;
  f32x4 c[4] = {{0,0,0,0},{0,0,0,0},{0,0,0,0},{0,0,0,0}};
  for (int ks = 0; ks < KS; ++ks) {
    const float* xp = x + (size_t)(r0 + m) * K + ks * 32 + q * 8;
    float4 v0 = *(const float4*)xp;
    float4 v1 = *(const float4*)(xp + 4);
    float vv[8] = {v0.x, v0.y, v0.z, v0.w, v1.x, v1.y, v1.z, v1.w};
    union { ushort_t s[8]; bf16x8 v; } ah, al;
    #pragma unroll
    for (int j = 0; j < 8; ++j) {
      unsigned hb = f2bf_bits(vv[j]);
      ah.s[j] = (ushort_t)hb;
      al.s[j] = (ushort_t)f2bf_bits(vv[j] - bf2f((ushort_t)hb));
    }
    #pragma unroll
    for (int nt = 0; nt < 4; ++nt) {
      const ushort_t* fb = fw + ((size_t)(nt * KS + ks) * 64 + lane) * 8;
      bf16x8 bh = ld_frag(fb);
      bf16x8 blo = ld_frag(fb + PLANE);
      c[nt] = MFMA16(ah.v, bh, c[nt]);
      c[nt] = MFMA16(ah.v, blo, c[nt]);
      c[nt] = MFMA16(al.v, bh, c[nt]);
    }
  }
  #pragma unroll
  for (int nt = 0; nt < 4; ++nt) {
    float bias = b[nt * 16 + m];
    #pragma unroll
    for (int r = 0; r < 4; ++r) {
      float o = fmaxf(c[nt][r] + bias, 0.0f);
      y[(size_t)(r0 + q * 4 + r) * H + nt * 16 + m] = (ushort_t)f2bf_bits(o);
    }
  }
}

__global__ __launch_bounds__(256)
void sage_pat_mfma(const ushort_t* __restrict__ agg, const ushort_t* __restrict__ x,
                   const ushort_t* __restrict__ fW1, const ushort_t* __restrict__ fW2,
                   const float* __restrict__ b1,
                   const float* __restrict__ g, const float* __restrict__ bb,
                   ushort_t* __restrict__ out, int N) {
  const int PLANE = 4096;
  const int wid = threadIdx.x >> 6, lane = threadIdx.x & 63;
  const int r0 = blockIdx.x * 64 + wid * 16;
  if (r0 >= N) return;
  const int m = lane & 15, q = lane >> 4;
  const ushort_t* ap = agg + (size_t)(r0 + m) * H + q * 8;
  const ushort_t* xp = x + (size_t)(r0 + m) * H + q * 8;
  bf16x8 A[2], X[2];
  A[0] = ld_frag(ap); A[1] = ld_frag(ap + 32);
  X[0] = ld_frag(xp); X[1] = ld_frag(xp + 32);
  f32x4 c[4] = {{0,0,0,0},{0,0,0,0},{0,0,0,0},{0,0,0,0}};
  #pragma unroll
  for (int nt = 0; nt < 4; ++nt) {
    #pragma unroll
    for (int ks = 0; ks < 2; ++ks) {
      const size_t fo = ((size_t)(nt * 2 + ks) * 64 + lane) * 8;
      bf16x8 bh = ld_frag(fW1 + fo), blo = ld_frag(fW1 + PLANE + fo);
      c[nt] = MFMA16(A[ks], bh, c[nt]);
      c[nt] = MFMA16(A[ks], blo, c[nt]);
      bh = ld_frag(fW2 + fo); blo = ld_frag(fW2 + PLANE + fo);
      c[nt] = MFMA16(X[ks], bh, c[nt]);
      c[nt] = MFMA16(X[ks], blo, c[nt]);
    }
  }
  float n2s[4] = {0, 0, 0, 0};
  #pragma unroll
  for (int nt = 0; nt < 4; ++nt) {
    float bias = b1[nt * 16 + m];
    #pragma unroll
    for (int r = 0; r < 4; ++r) {
      c[nt][r] += bias;
      n2s[r] = fmaf(c[nt][r], c[nt][r], n2s[r]);
    }
  }
  #pragma unroll
  for (int off = 1; off < 16; off <<= 1)
    #pragma unroll
    for (int r = 0; r < 4; ++r) n2s[r] += __shfl_xor(n2s[r], off);
  float rv[4];
  #pragma unroll
  for (int r = 0; r < 4; ++r) rv[r] = 1.0f / fmaxf(sqrtf(n2s[r]), 1e-12f);
  float y[4][4];
  float s1[4] = {0,0,0,0}, s2[4] = {0,0,0,0};
  #pragma unroll
  for (int nt = 0; nt < 4; ++nt)
    #pragma unroll
    for (int r = 0; r < 4; ++r) {
      float v = fmaxf(c[nt][r] * rv[r], 0.0f);
      y[nt][r] = v;
      s1[r] += v;
      s2[r] = fmaf(v, v, s2[r]);
    }
  #pragma unroll
  for (int off = 1; off < 16; off <<= 1)
    #pragma unroll
    for (int r = 0; r < 4; ++r) {
      s1[r] += __shfl_xor(s1[r], off);
      s2[r] += __shfl_xor(s2[r], off);
    }
  float mean[4], sig[4];
  #pragma unroll
  for (int r = 0; r < 4; ++r) {
    mean[r] = s1[r] * (1.0f / H);
    float var = s2[r] * (1.0f / H) - mean[r] * mean[r];
    sig[r] = rsqrtf(var + 1e-5f);
  }
  #pragma unroll
  for (int nt = 0; nt < 4; ++nt) {
    float gv = g[nt * 16 + m], bv = bb[nt * 16 + m];
    #pragma unroll
    for (int r = 0; r < 4; ++r) {
      float o = (y[nt][r] - mean[r]) * sig[r] * gv + bv;
      out[(size_t)(r0 + q * 4 + r) * H + nt * 16 + m] = (ushort_t)f2bf_bits(o);
    }
  }
}

__global__ __launch_bounds__(256)
void sage_stay_mfma(const ushort_t* __restrict__ agg2, const ushort_t* __restrict__ agg3,
                    const ushort_t* __restrict__ x,
                    const ushort_t* __restrict__ fWl2, const ushort_t* __restrict__ fWr2,
                    const ushort_t* __restrict__ fWl3, const ushort_t* __restrict__ fWr3,
                    const float* __restrict__ bl2, const float* __restrict__ bl3,
                    const float* __restrict__ g, const float* __restrict__ bb,
                    ushort_t* __restrict__ out, int N) {
  const int PLANE = 4096;
  const int wid = threadIdx.x >> 6, lane = threadIdx.x & 63;
  const int r0 = blockIdx.x * 64 + wid * 16;
  if (r0 >= N) return;
  const int m = lane & 15, q = lane >> 4;
  const ushort_t* a2p = agg2 + (size_t)(r0 + m) * H + q * 8;
  const ushort_t* a3p = agg3 + (size_t)(r0 + m) * H + q * 8;
  const ushort_t* xp  = x    + (size_t)(r0 + m) * H + q * 8;
  bf16x8 A2[2], A3[2], X[2];
  A2[0] = ld_frag(a2p); A2[1] = ld_frag(a2p + 32);
  A3[0] = ld_frag(a3p); A3[1] = ld_frag(a3p + 32);
  X[0]  = ld_frag(xp);  X[1]  = ld_frag(xp + 32);
  f32x4 c2[4] = {{0,0,0,0},{0,0,0,0},{0,0,0,0},{0,0,0,0}};
  f32x4 c3[4] = {{0,0,0,0},{0,0,0,0},{0,0,0,0},{0,0,0,0}};
  #pragma unroll
  for (int nt = 0; nt < 4; ++nt) {
    #pragma unroll
    for (int ks = 0; ks < 2; ++ks) {
      const size_t fo = ((size_t)(nt * 2 + ks) * 64 + lane) * 8;
      bf16x8 bh = ld_frag(fWl2 + fo), blo = ld_frag(fWl2 + PLANE + fo);
      c2[nt] = MFMA16(A2[ks], bh, c2[nt]);
      c2[nt] = MFMA16(A2[ks], blo, c2[nt]);
      bh = ld_frag(fWr2 + fo); blo = ld_frag(fWr2 + PLANE + fo);
      c2[nt] = MFMA16(X[ks], bh, c2[nt]);
      c2[nt] = MFMA16(X[ks], blo, c2[nt]);
      bh = ld_frag(fWl3 + fo); blo = ld_frag(fWl3 + PLANE + fo);
      c3[nt] = MFMA16(A3[ks], bh, c3[nt]);
      c3[nt] = MFMA16(A3[ks], blo, c3[nt]);
      bh = ld_frag(fWr3 + fo); blo = ld_frag(fWr3 + PLANE + fo);
      c3[nt] = MFMA16(X[ks], bh, c3[nt]);
      c3[nt] = MFMA16(X[ks], blo, c3[nt]);
    }
  }
  float n2s[4] = {0,0,0,0}, n3s[4] = {0,0,0,0};
  #pragma unroll
  for (int nt = 0; nt < 4; ++nt) {
    float b2 = bl2[nt * 16 + m], b3 = bl3[nt * 16 + m];
    #pragma unroll
    for (int r = 0; r < 4; ++r) {
      c2[nt][r] += b2;
      c3[nt][r] += b3;
      n2s[r] = fmaf(c2[nt][r], c2[nt][r], n2s[r]);
      n3s[r] = fmaf(c3[nt][r], c3[nt][r], n3s[r]);
    }
  }
  #pragma unroll
  for (int off = 1; off < 16; off <<= 1)
    #pragma unroll
    for (int r = 0; r < 4; ++r) {
      n2s[r] += __shfl_xor(n2s[r], off);
      n3s[r] += __shfl_xor(n3s[r], off);
    }
  float r2v[4], r3v[4];
  #pragma unroll
  for (int r = 0; r < 4; ++r) {
    r2v[r] = 0.5f / fmaxf(sqrtf(n2s[r]), 1e-12f);
    r3v[r] = 0.5f / fmaxf(sqrtf(n3s[r]), 1e-12f);
  }
  float y[4][4];
  float s1[4] = {0,0,0,0}, s2[4] = {0,0,0,0};
  #pragma unroll
  for (int nt = 0; nt < 4; ++nt)
    #pragma unroll
    for (int r = 0; r < 4; ++r) {
      float v = fmaxf(fmaf(c2[nt][r], r2v[r], c3[nt][r] * r3v[r]), 0.0f);
      y[nt][r] = v;
      s1[r] += v;
      s2[r] = fmaf(v, v, s2[r]);
    }
  #pragma unroll
  for (int off = 1; off < 16; off <<= 1)
    #pragma unroll
    for (int r = 0; r < 4; ++r) {
      s1[r] += __shfl_xor(s1[r], off);
      s2[r] += __shfl_xor(s2[r], off);
    }
  float mean[4], sig[4];
  #pragma unroll
  for (int r = 0; r < 4; ++r) {
    mean[r] = s1[r] * (1.0f / H);
    float var = s2[r] * (1.0f / H) - mean[r] * mean[r];
    sig[r] = rsqrtf(var + 1e-5f);
  }
  #pragma unroll
  for (int nt = 0; nt < 4; ++nt) {
    float gv = g[nt * 16 + m], bv = bb[nt * 16 + m];
    #pragma unroll
    for (int r = 0; r < 4; ++r) {
      float o = (y[nt][r] - mean[r]) * sig[r] * gv + bv;
      out[(size_t)(r0 + q * 4 + r) * H + nt * 16 + m] = (ushort_t)f2bf_bits(o);
    }
  }
}

__global__ __launch_bounds__(256)
void reg_kernel(const ushort_t* __restrict__ hs, const float* __restrict__ Wreg,
                const float* __restrict__ breg, float* __restrict__ out, int N) {
  const int lane = threadIdx.x & 63;
  const int node = blockIdx.x * 4 + (threadIdx.x >> 6);
  if (node >= N) return;
  float t = bf2f(hs[(size_t)node * H + lane]) * Wreg[lane];
  t = wave_sum(t);
  if (lane == 0) out[node] = t + breg[0];
}

// -----------------------------------------------------------------------------

extern "C" void kernel_launch(void* const* d_in, const int* in_sizes, int n_in,
                              void* d_out, int out_size, void* d_ws, size_t ws_size,
                              hipStream_t stream) {
  const float* x_stay  = (const float*)d_in[0];
  const float* x_pat   = (const float*)d_in[1];
  const float* Wp_stay = (const float*)d_in[2];
  const float* bp_stay = (const float*)d_in[3];
  const float* Wp_pat  = (const float*)d_in[4];
  const float* bp_pat  = (const float*)d_in[5];
  const float* Wl      = (const float*)d_in[6];
  const float* bl      = (const float*)d_in[7];
  const float* Wr      = (const float*)d_in[8];
  const float* ln_g    = (const float*)d_in[9];
  const float* ln_b    = (const float*)d_in[10];
  const float* Wreg    = (const float*)d_in[11];
  const float* breg    = (const float*)d_in[12];
  const int* e1s = (const int*)d_in[13];
  const int* e1d = (const int*)d_in[14];
  const int* e2s = (const int*)d_in[15];
  const int* e2d = (const int*)d_in[16];
  const int* e3s = (const int*)d_in[17];
  const int* e3d = (const int*)d_in[18];
  float* out = (float*)d_out;

  const size_t S = (size_t)N_STAY * H;
  const size_t P = (size_t)N_PAT * H;

  ushort_t* hs   = (ushort_t*)d_ws;
  ushort_t* hp   = hs + S;
  ushort_t* agg1 = hp + P;
  ushort_t* agg2 = agg1 + P;
  ushort_t* agg3 = agg2 + S;
  ushort_t* fragW = agg3 + S;
  ushort_t* fWpS = fragW;                // K=128: 2*8192
  ushort_t* fWpP = fragW + 16384;        // K=64:  2*4096
  ushort_t* fWlB = fragW + 24576;        // 6 * 8192
  ushort_t* fWrB = fragW + 24576 + 49152;
  int* ib    = (int*)(fragW + 122880);
  int* off1  = ib;                         // N_PAT+1
  int* off2  = off1 + (N_PAT + 1);         // N_STAY+1
  int* off3  = off2 + (N_STAY + 1);        // N_STAY+1
  int* bh1   = off3 + (N_STAY + 1);        // bh1..bh3 contiguous (memset together)
  int* bh2   = bh1 + NB_PAT;
  int* bh3   = bh2 + NB_STAY;
  int* bo1   = bh3 + NB_STAY;              // NB_PAT+1
  int* bo2   = bo1 + (NB_PAT + 1);         // NB_STAY+1
  int* bo3   = bo2 + (NB_STAY + 1);        // NB_STAY+1
  int* bc1   = bo3 + (NB_STAY + 1);        // cursors
  int* bc2   = bc1 + NB_PAT;
  int* bc3   = bc2 + NB_STAY;
  int* bv1   = bc3 + NB_STAY;              // packed binned values, E each
  int* bv2   = bv1 + N_EDGE;
  int* bv3   = bv2 + N_EDGE;
  int* csr1  = bv3 + N_EDGE;               // E each
  int* csr2  = csr1 + N_EDGE;
  int* csr3  = csr2 + N_EDGE;

  const int eb = (N_EDGE + 255) / 256;

  // weight preconversion (tiny)
  precvt_kernel<128><<<4, 256, 0, stream>>>(Wp_stay, fWpS, 1);
  precvt_kernel<64><<<2, 256, 0, stream>>>(Wp_pat, fWpP, 1);
  precvt_kernel<64><<<12, 256, 0, stream>>>(Wl, fWlB, 6);
  precvt_kernel<64><<<12, 256, 0, stream>>>(Wr, fWrB, 6);

  // CSR build: coarse bin + fine sort
  hipMemsetAsync(bh1, 0, (size_t)(NB_PAT + 2 * NB_STAY) * sizeof(int), stream);
  bhist3_kernel<<<3 * eb, 256, 0, stream>>>(e1d, e2d, e3d, bh1, bh2, bh3, eb);
  scan_one<<<1, 256, 0, stream>>>(bh1, NB_PAT, bo1, bc1, N_EDGE);
  scan_one<<<1, 256, 0, stream>>>(bh2, NB_STAY, bo2, bc2, N_EDGE);
  scan_one<<<1, 256, 0, stream>>>(bh3, NB_STAY, bo3, bc3, N_EDGE);
  scatter3_kernel<<<3 * eb, 256, 0, stream>>>(e1s, e1d, e2s, e2d, e3s, e3d,
                                              bc1, bc2, bc3, bv1, bv2, bv3, eb);
  fine3_kernel<<<NB_PAT + 2 * NB_STAY, 256, 0, stream>>>(
      bv1, bo1, bv2, bo2, bv3, bo3, csr1, off1, csr2, off2, csr3, off3);

  // input projections
  proj_mfma<128><<<(N_STAY + 63) / 64, 256, 0, stream>>>(x_stay, fWpS, bp_stay, hs, N_STAY);
  proj_mfma<64><<<(N_PAT + 63) / 64, 256, 0, stream>>>(x_pat, fWpP, bp_pat, hp, N_PAT);

  const int AGG_S = (N_STAY * 64 + 255) / 256;
  const int AGG_P = (N_PAT * 64 + 255) / 256;

  for (int l = 0; l < 2; ++l) {
    ushort_t* fWl0 = fWlB + (size_t)(l * 3 + 0) * 8192;
    ushort_t* fWl1 = fWlB + (size_t)(l * 3 + 1) * 8192;
    ushort_t* fWl2 = fWlB + (size_t)(l * 3 + 2) * 8192;
    ushort_t* fWr0 = fWrB + (size_t)(l * 3 + 0) * 8192;
    ushort_t* fWr1 = fWrB + (size_t)(l * 3 + 1) * 8192;
    ushort_t* fWr2 = fWrB + (size_t)(l * 3 + 2) * 8192;
    const float* bl0 = bl + (size_t)(l * 3 + 0) * H;
    const float* bl1 = bl + (size_t)(l * 3 + 1) * H;
    const float* bl2 = bl + (size_t)(l * 3 + 2) * H;
    const float* g  = ln_g + (size_t)l * H;
    const float* bb = ln_b + (size_t)l * H;

    agg_kernel<<<AGG_P, 256, 0, stream>>>(hs, off1, csr1, agg1, N_PAT);
    agg_kernel<<<AGG_S, 256, 0, stream>>>(hp, off2, csr2, agg2, N_STAY);
    agg_kernel<<<AGG_S, 256, 0, stream>>>(hs, off3, csr3, agg3, N_STAY);

    sage_pat_mfma<<<(N_PAT + 63) / 64, 256, 0, stream>>>(
        agg1, hp, fWl0, fWr0, bl0, g, bb, hp, N_PAT);
    sage_stay_mfma<<<(N_STAY + 63) / 64, 256, 0, stream>>>(
        agg2, agg3, hs, fWl1, fWr1, fWl2, fWr2, bl1, bl2, g, bb, hs, N_STAY);
  }

  reg_kernel<<<(N_STAY + 3) / 4, 256, 0, stream>>>(hs, Wreg, breg, out, N_STAY);
}

// Round 7
// 773.137 us; speedup vs baseline: 1.5657x; 1.5657x over previous
//
#include <hip/hip_runtime.h>

#define H 64
#define N_STAY 200000
#define N_PAT  100000
#define N_EDGE 1000000
#define NBC_STAY 98    // ceil(200000/2048)
#define NBC_PAT  49    // ceil(100000/2048)
#define PB 245         // ceil(1e6/4096) edge blocks of 4096

typedef unsigned short ushort_t;
typedef __attribute__((ext_vector_type(8))) short bf16x8;
typedef __attribute__((ext_vector_type(4))) float f32x4;

__device__ __forceinline__ float wave_sum(float v) {
  #pragma unroll
  for (int off = 32; off > 0; off >>= 1) v += __shfl_xor(v, off);
  return v;
}

__device__ __forceinline__ float bf2f(ushort_t u) {
  union { unsigned int i; float f; } c;
  c.i = ((unsigned int)u) << 16;
  return c.f;
}
__device__ __forceinline__ unsigned int f2bf_bits(float f) {
  union { float v; unsigned int i; } c; c.v = f;
  unsigned int r = c.i + 0x7fffu + ((c.i >> 16) & 1u);  // RNE
  return r >> 16;
}
__device__ __forceinline__ unsigned int pack2(float lo, float hi) {
  return f2bf_bits(lo) | (f2bf_bits(hi) << 16);
}
__device__ __forceinline__ void unpack8(uint4 q, float* f) {
  union { unsigned int i; float v; } c;
  c.i = q.x << 16;          f[0] = c.v;
  c.i = q.x & 0xffff0000u;  f[1] = c.v;
  c.i = q.y << 16;          f[2] = c.v;
  c.i = q.y & 0xffff0000u;  f[3] = c.v;
  c.i = q.z << 16;          f[4] = c.v;
  c.i = q.z & 0xffff0000u;  f[5] = c.v;
  c.i = q.w << 16;          f[6] = c.v;
  c.i = q.w & 0xffff0000u;  f[7] = c.v;
}
__device__ __forceinline__ bf16x8 ld_frag(const ushort_t* p) {
  union { uint4 u; bf16x8 v; } c;
  c.u = *(const uint4*)p;
  return c.v;
}

// ---------------- CSR build -------------------------------------------------
// Three stages, all XCD-write-amplification-aware:
//  1) blockhist3: LDS hist per 4096-edge block -> global coarse hist (2048-node buckets)
//  2) phaseA3: LDS-sort each 4096-edge block by coarse bucket; one atomicAdd per
//     group; write ~170B contiguous runs (single-writer lines except boundaries)
//  3) phaseB3: one block per coarse bucket -> node-sorted csr + off[] directly
//     (all writes to the bucket region come from ONE block/XCD)

__global__ __launch_bounds__(256)
void blockhist3_kernel(const int* __restrict__ d1, const int* __restrict__ d2,
                       const int* __restrict__ d3,
                       int* __restrict__ h1, int* __restrict__ h2, int* __restrict__ h3) {
  int which = blockIdx.x / PB;
  int blk = blockIdx.x % PB;
  const int* dp = (which == 0) ? d1 : (which == 1) ? d2 : d3;
  int* hp = (which == 0) ? h1 : (which == 1) ? h2 : h3;
  int nbc = (which == 0) ? NBC_PAT : NBC_STAY;
  __shared__ int lh[128];
  if (threadIdx.x < 128) lh[threadIdx.x] = 0;
  __syncthreads();
  int base = blk * 4096;
  int n = min(4096, N_EDGE - base);
  for (int i = threadIdx.x; i < n; i += 256)
    atomicAdd(&lh[dp[base + i] >> 11], 1);
  __syncthreads();
  if (threadIdx.x < nbc && lh[threadIdx.x])
    atomicAdd(&hp[threadIdx.x], lh[threadIdx.x]);
}

// single-block exclusive scan, n <= 4096; writes off[0..n] and cur[0..n-1]
__global__ __launch_bounds__(256)
void scan_one(const int* __restrict__ in, int n, int* __restrict__ off,
              int* __restrict__ cur, int total) {
  int tid = threadIdx.x;
  int base = tid * 16;
  int vals[16]; int s = 0;
  #pragma unroll
  for (int i = 0; i < 16; ++i) {
    int idx = base + i;
    vals[i] = (idx < n) ? in[idx] : 0;
    s += vals[i];
  }
  int lane = tid & 63, w = tid >> 6;
  int incl = s;
  #pragma unroll
  for (int o = 1; o < 64; o <<= 1) {
    int t = __shfl_up(incl, o);
    if (lane >= o) incl += t;
  }
  __shared__ int wtot[4];
  if (lane == 63) wtot[w] = incl;
  __syncthreads();
  int wbase = 0;
  for (int i = 0; i < w; ++i) wbase += wtot[i];
  int run = wbase + incl - s;
  #pragma unroll
  for (int i = 0; i < 16; ++i) {
    int idx = base + i;
    if (idx < n) { off[idx] = run; cur[idx] = run; run += vals[i]; }
  }
  if (tid == 0) off[n] = total;
}

// packed value = src | ((dst & 2047) << 18); bucket = dst >> 11
__global__ __launch_bounds__(256)
void phaseA3_kernel(const int* __restrict__ s1, const int* __restrict__ d1,
                    const int* __restrict__ s2, const int* __restrict__ d2,
                    const int* __restrict__ s3, const int* __restrict__ d3,
                    int* __restrict__ c1, int* __restrict__ c2, int* __restrict__ c3,
                    int* __restrict__ v1, int* __restrict__ v2, int* __restrict__ v3) {
  int which = blockIdx.x / PB;
  int blk = blockIdx.x % PB;
  const int* sp = (which == 0) ? s1 : (which == 1) ? s2 : s3;
  const int* dp = (which == 0) ? d1 : (which == 1) ? d2 : d3;
  int* cp = (which == 0) ? c1 : (which == 1) ? c2 : c3;
  int* vp = (which == 0) ? v1 : (which == 1) ? v2 : v3;
  int nbc = (which == 0) ? NBC_PAT : NBC_STAY;
  __shared__ int vals[4096];
  __shared__ unsigned char bkt[4096];
  __shared__ int lh[128], lbase[128], lcur[128], gbase[128];
  __shared__ int wt[2];
  const int tid = threadIdx.x;
  if (tid < 128) lh[tid] = 0;
  __syncthreads();
  int base = blk * 4096;
  int n = min(4096, N_EDGE - base);
  int pv[16], pbk[16];
  #pragma unroll
  for (int i = 0; i < 16; ++i) {
    int idx = i * 256 + tid;
    if (idx < n) {
      int e = base + idx;
      int d = dp[e], s = sp[e];
      pv[i] = s | ((d & 2047) << 18);
      pbk[i] = d >> 11;
      atomicAdd(&lh[pbk[i]], 1);
    } else pbk[i] = -1;
  }
  __syncthreads();
  // exclusive scan of lh[0..nbc) (nbc <= 98 < 128) via two waves
  {
    int lane = tid & 63, w = tid >> 6;
    int x = (tid < 128 && tid < nbc) ? lh[tid] : 0;
    int incl = x;
    #pragma unroll
    for (int o = 1; o < 64; o <<= 1) {
      int t = __shfl_up(incl, o);
      if (lane >= o) incl += t;
    }
    if (w < 2 && lane == 63) wt[w] = incl;
    __syncthreads();
    if (tid < 128) {
      int ex = incl - x + ((w == 1) ? wt[0] : 0);
      lbase[tid] = ex;
      lcur[tid] = ex;
    }
  }
  __syncthreads();
  // place into LDS sorted by bucket
  #pragma unroll
  for (int i = 0; i < 16; ++i) {
    if (pbk[i] >= 0) {
      int r = atomicAdd(&lcur[pbk[i]], 1);
      vals[r] = pv[i];
      bkt[r] = (unsigned char)pbk[i];
    }
  }
  __syncthreads();
  // reserve global space: one atomic per non-empty bucket group
  if (tid < nbc) {
    int cnt = lh[tid];
    gbase[tid] = cnt ? atomicAdd(&cp[tid], cnt) : 0;
  }
  __syncthreads();
  // contiguous run copy-out (consecutive i -> mostly consecutive addresses)
  for (int i = tid; i < n; i += 256) {
    int b = bkt[i];
    vp[gbase[b] + i - lbase[b]] = vals[i];
  }
}

// one block per coarse bucket: node-sorted csr + off[]
__global__ __launch_bounds__(256)
void phaseB3_kernel(const int* __restrict__ v1, const int* __restrict__ bo1,
                    const int* __restrict__ v2, const int* __restrict__ bo2,
                    const int* __restrict__ v3, const int* __restrict__ bo3,
                    int* __restrict__ csr1, int* __restrict__ off1,
                    int* __restrict__ csr2, int* __restrict__ off2,
                    int* __restrict__ csr3, int* __restrict__ off3) {
  int b = blockIdx.x;
  const int* v; const int* bo; int* csr; int* off; int N; int lb;
  if (b < NBC_PAT)                 { v = v1; bo = bo1; csr = csr1; off = off1; N = N_PAT;  lb = b; }
  else if (b < NBC_PAT + NBC_STAY) { v = v2; bo = bo2; csr = csr2; off = off2; N = N_STAY; lb = b - NBC_PAT; }
  else                             { v = v3; bo = bo3; csr = csr3; off = off3; N = N_STAY; lb = b - NBC_PAT - NBC_STAY; }
  const int tid = threadIdx.x;
  __shared__ int lh[2048];
  __shared__ int lcur[2048];
  __shared__ int wt[4];
  #pragma unroll
  for (int j = 0; j < 8; ++j) lh[tid + j * 256] = 0;
  __syncthreads();
  const int rb = bo[lb], re = bo[lb + 1];
  for (int i = rb + tid; i < re; i += 256)
    atomicAdd(&lh[(v[i] >> 18) & 2047], 1);
  __syncthreads();
  // block exclusive scan over 2048 -> lcur (+rb), emit off[]
  const int node_base = lb * 2048;
  const int b8 = tid * 8;
  int ex[8]; int run = 0;
  #pragma unroll
  for (int j = 0; j < 8; ++j) { ex[j] = run; run += lh[b8 + j]; }
  int lane = tid & 63, w = tid >> 6;
  int incl = run;
  #pragma unroll
  for (int o = 1; o < 64; o <<= 1) {
    int t = __shfl_up(incl, o);
    if (lane >= o) incl += t;
  }
  if (lane == 63) wt[w] = incl;
  __syncthreads();
  int wb = 0;
  for (int i = 0; i < w; ++i) wb += wt[i];
  const int tex = rb + wb + incl - run;
  #pragma unroll
  for (int j = 0; j < 8; ++j) {
    int pos = tex + ex[j];
    lcur[b8 + j] = pos;
    int node = node_base + b8 + j;
    if (node < N) off[node] = pos;
  }
  __syncthreads();
  for (int i = rb + tid; i < re; i += 256) {
    int val = v[i];
    int pos = atomicAdd(&lcur[(val >> 18) & 2047], 1);
    csr[pos] = val & 0x3FFFF;
  }
  if (b == 0 && tid == 0) {
    off1[N_PAT] = N_EDGE;
    off2[N_STAY] = N_EDGE;
    off3[N_STAY] = N_EDGE;
  }
}

// ---------------- weight preconversion to MFMA B-fragments (hi+lo bf16) -----

template<int K>
__global__ __launch_bounds__(256)
void precvt_kernel(const float* __restrict__ src, ushort_t* __restrict__ dst, int nmat) {
  const int KS = K / 32;
  const int FU = KS * 4;
  const int PLANE = FU * 64 * 8;
  int fu = blockIdx.x * 4 + (threadIdx.x >> 6);
  int lane = threadIdx.x & 63;
  int mi = fu / FU;
  if (mi >= nmat) return;
  int fid = fu % FU;
  int ntile = fid / KS;
  int kstep = fid % KS;
  int q = lane >> 4, n = ntile * 16 + (lane & 15);
  const float* W = src + (size_t)mi * K * H;
  union { ushort_t s[8]; uint4 u; } hi, lo;
  #pragma unroll
  for (int j = 0; j < 8; ++j) {
    float v = W[(size_t)(kstep * 32 + q * 8 + j) * H + n];
    unsigned hb = f2bf_bits(v);
    hi.s[j] = (ushort_t)hb;
    lo.s[j] = (ushort_t)f2bf_bits(v - bf2f((ushort_t)hb));
  }
  ushort_t* base = dst + (size_t)mi * 2 * PLANE + ((size_t)fid * 64 + lane) * 8;
  *(uint4*)base = hi.u;
  *(uint4*)(base + PLANE) = lo.u;
}

// ---------------- aggregation: wave per dst node, 8 edges x 8 lanes ----------

__global__ __launch_bounds__(256)
void agg_kernel(const ushort_t* __restrict__ x, const int* __restrict__ off,
                const int* __restrict__ csr, ushort_t* __restrict__ agg, int N) {
  const int node = (int)((blockIdx.x * 256 + threadIdx.x) >> 6);
  const int lane = threadIdx.x & 63;
  if (node >= N) return;
  const int o0 = off[node], o1 = off[node + 1];
  const int slot = lane >> 3;
  const int fg = lane & 7;
  float acc[8] = {0, 0, 0, 0, 0, 0, 0, 0};
  for (int t = o0 + slot; t < o1; t += 8) {
    int s = csr[t];
    uint4 q = *(const uint4*)(x + (size_t)s * H + fg * 8);
    float f[8];
    unpack8(q, f);
    #pragma unroll
    for (int j = 0; j < 8; ++j) acc[j] += f[j];
  }
  #pragma unroll
  for (int o = 8; o < 64; o <<= 1)
    #pragma unroll
    for (int j = 0; j < 8; ++j) acc[j] += __shfl_xor(acc[j], o);
  if (slot == 0) {
    const float inv = 1.0f / fmaxf((float)(o1 - o0), 1.0f);
    uint4 q;
    q.x = pack2(acc[0] * inv, acc[1] * inv);
    q.y = pack2(acc[2] * inv, acc[3] * inv);
    q.z = pack2(acc[4] * inv, acc[5] * inv);
    q.w = pack2(acc[6] * inv, acc[7] * inv);
    *(uint4*)(agg + (size_t)node * H + fg * 8) = q;
  }
}

// ---------------- MFMA dense kernels ----------------------------------------

#define MFMA16(a, b, c) __builtin_amdgcn_mfma_f32_16x16x32_bf16((a), (b), (c), 0, 0, 0)

template<int K>
__global__ __launch_bounds__(256)
void proj_mfma(const float* __restrict__ x, const ushort_t* __restrict__ fw,
               const float* __restrict__ b, ushort_t* __restrict__ y, int N) {
  const int KS = K / 32;
  const int PLANE = KS * 4 * 64 * 8;
  const int wid = threadIdx.x >> 6, lane = threadIdx.x & 63;
  const int r0 = blockIdx.x * 64 + wid * 16;
  if (r0 >= N) return;
  const int m = lane & 15, q = lane >> 4;
  f32x4 c[4] = {{0,0,0,0},{0,0,0,0},{0,0,0,0},{0,0,0,0}};
  for (int ks = 0; ks < KS; ++ks) {
    const float* xp = x + (size_t)(r0 + m) * K + ks * 32 + q * 8;
    float4 v0 = *(const float4*)xp;
    float4 v1 = *(const float4*)(xp + 4);
    float vv[8] = {v0.x, v0.y, v0.z, v0.w, v1.x, v1.y, v1.z, v1.w};
    union { ushort_t s[8]; bf16x8 v; } ah, al;
    #pragma unroll
    for (int j = 0; j < 8; ++j) {
      unsigned hb = f2bf_bits(vv[j]);
      ah.s[j] = (ushort_t)hb;
      al.s[j] = (ushort_t)f2bf_bits(vv[j] - bf2f((ushort_t)hb));
    }
    #pragma unroll
    for (int nt = 0; nt < 4; ++nt) {
      const ushort_t* fb = fw + ((size_t)(nt * KS + ks) * 64 + lane) * 8;
      bf16x8 bh = ld_frag(fb);
      bf16x8 blo = ld_frag(fb + PLANE);
      c[nt] = MFMA16(ah.v, bh, c[nt]);
      c[nt] = MFMA16(ah.v, blo, c[nt]);
      c[nt] = MFMA16(al.v, bh, c[nt]);
    }
  }
  #pragma unroll
  for (int nt = 0; nt < 4; ++nt) {
    float bias = b[nt * 16 + m];
    #pragma unroll
    for (int r = 0; r < 4; ++r) {
      float o = fmaxf(c[nt][r] + bias, 0.0f);
      y[(size_t)(r0 + q * 4 + r) * H + nt * 16 + m] = (ushort_t)f2bf_bits(o);
    }
  }
}

__global__ __launch_bounds__(256)
void sage_pat_mfma(const ushort_t* __restrict__ agg, const ushort_t* __restrict__ x,
                   const ushort_t* __restrict__ fW1, const ushort_t* __restrict__ fW2,
                   const float* __restrict__ b1,
                   const float* __restrict__ g, const float* __restrict__ bb,
                   ushort_t* __restrict__ out, int N) {
  const int PLANE = 4096;
  const int wid = threadIdx.x >> 6, lane = threadIdx.x & 63;
  const int r0 = blockIdx.x * 64 + wid * 16;
  if (r0 >= N) return;
  const int m = lane & 15, q = lane >> 4;
  const ushort_t* ap = agg + (size_t)(r0 + m) * H + q * 8;
  const ushort_t* xp = x + (size_t)(r0 + m) * H + q * 8;
  bf16x8 A[2], X[2];
  A[0] = ld_frag(ap); A[1] = ld_frag(ap + 32);
  X[0] = ld_frag(xp); X[1] = ld_frag(xp + 32);
  f32x4 c[4] = {{0,0,0,0},{0,0,0,0},{0,0,0,0},{0,0,0,0}};
  #pragma unroll
  for (int nt = 0; nt < 4; ++nt) {
    #pragma unroll
    for (int ks = 0; ks < 2; ++ks) {
      const size_t fo = ((size_t)(nt * 2 + ks) * 64 + lane) * 8;
      bf16x8 bh = ld_frag(fW1 + fo), blo = ld_frag(fW1 + PLANE + fo);
      c[nt] = MFMA16(A[ks], bh, c[nt]);
      c[nt] = MFMA16(A[ks], blo, c[nt]);
      bh = ld_frag(fW2 + fo); blo = ld_frag(fW2 + PLANE + fo);
      c[nt] = MFMA16(X[ks], bh, c[nt]);
      c[nt] = MFMA16(X[ks], blo, c[nt]);
    }
  }
  float n2s[4] = {0, 0, 0, 0};
  #pragma unroll
  for (int nt = 0; nt < 4; ++nt) {
    float bias = b1[nt * 16 + m];
    #pragma unroll
    for (int r = 0; r < 4; ++r) {
      c[nt][r] += bias;
      n2s[r] = fmaf(c[nt][r], c[nt][r], n2s[r]);
    }
  }
  #pragma unroll
  for (int off = 1; off < 16; off <<= 1)
    #pragma unroll
    for (int r = 0; r < 4; ++r) n2s[r] += __shfl_xor(n2s[r], off);
  float rv[4];
  #pragma unroll
  for (int r = 0; r < 4; ++r) rv[r] = 1.0f / fmaxf(sqrtf(n2s[r]), 1e-12f);
  float y[4][4];
  float s1[4] = {0,0,0,0}, s2[4] = {0,0,0,0};
  #pragma unroll
  for (int nt = 0; nt < 4; ++nt)
    #pragma unroll
    for (int r = 0; r < 4; ++r) {
      float v = fmaxf(c[nt][r] * rv[r], 0.0f);
      y[nt][r] = v;
      s1[r] += v;
      s2[r] = fmaf(v, v, s2[r]);
    }
  #pragma unroll
  for (int off = 1; off < 16; off <<= 1)
    #pragma unroll
    for (int r = 0; r < 4; ++r) {
      s1[r] += __shfl_xor(s1[r], off);
      s2[r] += __shfl_xor(s2[r], off);
    }
  float mean[4], sig[4];
  #pragma unroll
  for (int r = 0; r < 4; ++r) {
    mean[r] = s1[r] * (1.0f / H);
    float var = s2[r] * (1.0f / H) - mean[r] * mean[r];
    sig[r] = rsqrtf(var + 1e-5f);
  }
  #pragma unroll
  for (int nt = 0; nt < 4; ++nt) {
    float gv = g[nt * 16 + m], bv = bb[nt * 16 + m];
    #pragma unroll
    for (int r = 0; r < 4; ++r) {
      float o = (y[nt][r] - mean[r]) * sig[r] * gv + bv;
      out[(size_t)(r0 + q * 4 + r) * H + nt * 16 + m] = (ushort_t)f2bf_bits(o);
    }
  }
}

__global__ __launch_bounds__(256)
void sage_stay_mfma(const ushort_t* __restrict__ agg2, const ushort_t* __restrict__ agg3,
                    const ushort_t* __restrict__ x,
                    const ushort_t* __restrict__ fWl2, const ushort_t* __restrict__ fWr2,
                    const ushort_t* __restrict__ fWl3, const ushort_t* __restrict__ fWr3,
                    const float* __restrict__ bl2, const float* __restrict__ bl3,
                    const float* __restrict__ g, const float* __restrict__ bb,
                    ushort_t* __restrict__ out, int N) {
  const int PLANE = 4096;
  const int wid = threadIdx.x >> 6, lane = threadIdx.x & 63;
  const int r0 = blockIdx.x * 64 + wid * 16;
  if (r0 >= N) return;
  const int m = lane & 15, q = lane >> 4;
  const ushort_t* a2p = agg2 + (size_t)(r0 + m) * H + q * 8;
  const ushort_t* a3p = agg3 + (size_t)(r0 + m) * H + q * 8;
  const ushort_t* xp  = x    + (size_t)(r0 + m) * H + q * 8;
  bf16x8 A2[2], A3[2], X[2];
  A2[0] = ld_frag(a2p); A2[1] = ld_frag(a2p + 32);
  A3[0] = ld_frag(a3p); A3[1] = ld_frag(a3p + 32);
  X[0]  = ld_frag(xp);  X[1]  = ld_frag(xp + 32);
  f32x4 c2[4] = {{0,0,0,0},{0,0,0,0},{0,0,0,0},{0,0,0,0}};
  f32x4 c3[4] = {{0,0,0,0},{0,0,0,0},{0,0,0,0},{0,0,0,0}};
  #pragma unroll
  for (int nt = 0; nt < 4; ++nt) {
    #pragma unroll
    for (int ks = 0; ks < 2; ++ks) {
      const size_t fo = ((size_t)(nt * 2 + ks) * 64 + lane) * 8;
      bf16x8 bh = ld_frag(fWl2 + fo), blo = ld_frag(fWl2 + PLANE + fo);
      c2[nt] = MFMA16(A2[ks], bh, c2[nt]);
      c2[nt] = MFMA16(A2[ks], blo, c2[nt]);
      bh = ld_frag(fWr2 + fo); blo = ld_frag(fWr2 + PLANE + fo);
      c2[nt] = MFMA16(X[ks], bh, c2[nt]);
      c2[nt] = MFMA16(X[ks], blo, c2[nt]);
      bh = ld_frag(fWl3 + fo); blo = ld_frag(fWl3 + PLANE + fo);
      c3[nt] = MFMA16(A3[ks], bh, c3[nt]);
      c3[nt] = MFMA16(A3[ks], blo, c3[nt]);
      bh = ld_frag(fWr3 + fo); blo = ld_frag(fWr3 + PLANE + fo);
      c3[nt] = MFMA16(X[ks], bh, c3[nt]);
      c3[nt] = MFMA16(X[ks], blo, c3[nt]);
    }
  }
  float n2s[4] = {0,0,0,0}, n3s[4] = {0,0,0,0};
  #pragma unroll
  for (int nt = 0; nt < 4; ++nt) {
    float b2 = bl2[nt * 16 + m], b3 = bl3[nt * 16 + m];
    #pragma unroll
    for (int r = 0; r < 4; ++r) {
      c2[nt][r] += b2;
      c3[nt][r] += b3;
      n2s[r] = fmaf(c2[nt][r], c2[nt][r], n2s[r]);
      n3s[r] = fmaf(c3[nt][r], c3[nt][r], n3s[r]);
    }
  }
  #pragma unroll
  for (int off = 1; off < 16; off <<= 1)
    #pragma unroll
    for (int r = 0; r < 4; ++r) {
      n2s[r] += __shfl_xor(n2s[r], off);
      n3s[r] += __shfl_xor(n3s[r], off);
    }
  float r2v[4], r3v[4];
  #pragma unroll
  for (int r = 0; r < 4; ++r) {
    r2v[r] = 0.5f / fmaxf(sqrtf(n2s[r]), 1e-12f);
    r3v[r] = 0.5f / fmaxf(sqrtf(n3s[r]), 1e-12f);
  }
  float y[4][4];
  float s1[4] = {0,0,0,0}, s2[4] = {0,0,0,0};
  #pragma unroll
  for (int nt = 0; nt < 4; ++nt)
    #pragma unroll
    for (int r = 0; r < 4; ++r) {
      float v = fmaxf(fmaf(c2[nt][r], r2v[r], c3[nt][r] * r3v[r]), 0.0f);
      y[nt][r] = v;
      s1[r] += v;
      s2[r] = fmaf(v, v, s2[r]);
    }
  #pragma unroll
  for (int off = 1; off < 16; off <<= 1)
    #pragma unroll
    for (int r = 0; r < 4; ++r) {
      s1[r] += __shfl_xor(s1[r], off);
      s2[r] += __shfl_xor(s2[r], off);
    }
  float mean[4], sig[4];
  #pragma unroll
  for (int r = 0; r < 4; ++r) {
    mean[r] = s1[r] * (1.0f / H);
    float var = s2[r] * (1.0f / H) - mean[r] * mean[r];
    sig[r] = rsqrtf(var + 1e-5f);
  }
  #pragma unroll
  for (int nt = 0; nt < 4; ++nt) {
    float gv = g[nt * 16 + m], bv = bb[nt * 16 + m];
    #pragma unroll
    for (int r = 0; r < 4; ++r) {
      float o = (y[nt][r] - mean[r]) * sig[r] * gv + bv;
      out[(size_t)(r0 + q * 4 + r) * H + nt * 16 + m] = (ushort_t)f2bf_bits(o);
    }
  }
}

__global__ __launch_bounds__(256)
void reg_kernel(const ushort_t* __restrict__ hs, const float* __restrict__ Wreg,
                const float* __restrict__ breg, float* __restrict__ out, int N) {
  const int lane = threadIdx.x & 63;
  const int node = blockIdx.x * 4 + (threadIdx.x >> 6);
  if (node >= N) return;
  float t = bf2f(hs[(size_t)node * H + lane]) * Wreg[lane];
  t = wave_sum(t);
  if (lane == 0) out[node] = t + breg[0];
}

// -----------------------------------------------------------------------------

extern "C" void kernel_launch(void* const* d_in, const int* in_sizes, int n_in,
                              void* d_out, int out_size, void* d_ws, size_t ws_size,
                              hipStream_t stream) {
  const float* x_stay  = (const float*)d_in[0];
  const float* x_pat   = (const float*)d_in[1];
  const float* Wp_stay = (const float*)d_in[2];
  const float* bp_stay = (const float*)d_in[3];
  const float* Wp_pat  = (const float*)d_in[4];
  const float* bp_pat  = (const float*)d_in[5];
  const float* Wl      = (const float*)d_in[6];
  const float* bl      = (const float*)d_in[7];
  const float* Wr      = (const float*)d_in[8];
  const float* ln_g    = (const float*)d_in[9];
  const float* ln_b    = (const float*)d_in[10];
  const float* Wreg    = (const float*)d_in[11];
  const float* breg    = (const float*)d_in[12];
  const int* e1s = (const int*)d_in[13];
  const int* e1d = (const int*)d_in[14];
  const int* e2s = (const int*)d_in[15];
  const int* e2d = (const int*)d_in[16];
  const int* e3s = (const int*)d_in[17];
  const int* e3d = (const int*)d_in[18];
  float* out = (float*)d_out;

  const size_t S = (size_t)N_STAY * H;
  const size_t P = (size_t)N_PAT * H;

  ushort_t* hs   = (ushort_t*)d_ws;
  ushort_t* hp   = hs + S;
  ushort_t* agg1 = hp + P;
  ushort_t* agg2 = agg1 + P;
  ushort_t* agg3 = agg2 + S;
  ushort_t* fragW = agg3 + S;
  ushort_t* fWpS = fragW;                // K=128: 2*8192
  ushort_t* fWpP = fragW + 16384;        // K=64:  2*4096
  ushort_t* fWlB = fragW + 24576;        // 6 * 8192
  ushort_t* fWrB = fragW + 24576 + 49152;
  int* ib    = (int*)(fragW + 122880);
  int* off1  = ib;                         // N_PAT+1
  int* off2  = off1 + (N_PAT + 1);         // N_STAY+1
  int* off3  = off2 + (N_STAY + 1);        // N_STAY+1
  int* bh1   = off3 + (N_STAY + 1);        // coarse hists, contiguous
  int* bh2   = bh1 + NBC_PAT;
  int* bh3   = bh2 + NBC_STAY;
  int* bo1   = bh3 + NBC_STAY;             // NBC_PAT+1
  int* bo2   = bo1 + (NBC_PAT + 1);        // NBC_STAY+1
  int* bo3   = bo2 + (NBC_STAY + 1);       // NBC_STAY+1
  int* bc1   = bo3 + (NBC_STAY + 1);       // cursors
  int* bc2   = bc1 + NBC_PAT;
  int* bc3   = bc2 + NBC_STAY;
  int* bv1   = bc3 + NBC_STAY;             // binned packed values, E each
  int* bv2   = bv1 + N_EDGE;
  int* bv3   = bv2 + N_EDGE;
  int* csr1  = bv3 + N_EDGE;               // E each
  int* csr2  = csr1 + N_EDGE;
  int* csr3  = csr2 + N_EDGE;

  // weight preconversion (tiny)
  precvt_kernel<128><<<4, 256, 0, stream>>>(Wp_stay, fWpS, 1);
  precvt_kernel<64><<<2, 256, 0, stream>>>(Wp_pat, fWpP, 1);
  precvt_kernel<64><<<12, 256, 0, stream>>>(Wl, fWlB, 6);
  precvt_kernel<64><<<12, 256, 0, stream>>>(Wr, fWrB, 6);

  // CSR build
  hipMemsetAsync(bh1, 0, (size_t)(NBC_PAT + 2 * NBC_STAY) * sizeof(int), stream);
  blockhist3_kernel<<<3 * PB, 256, 0, stream>>>(e1d, e2d, e3d, bh1, bh2, bh3);
  scan_one<<<1, 256, 0, stream>>>(bh1, NBC_PAT, bo1, bc1, N_EDGE);
  scan_one<<<1, 256, 0, stream>>>(bh2, NBC_STAY, bo2, bc2, N_EDGE);
  scan_one<<<1, 256, 0, stream>>>(bh3, NBC_STAY, bo3, bc3, N_EDGE);
  phaseA3_kernel<<<3 * PB, 256, 0, stream>>>(e1s, e1d, e2s, e2d, e3s, e3d,
                                             bc1, bc2, bc3, bv1, bv2, bv3);
  phaseB3_kernel<<<NBC_PAT + 2 * NBC_STAY, 256, 0, stream>>>(
      bv1, bo1, bv2, bo2, bv3, bo3, csr1, off1, csr2, off2, csr3, off3);

  // input projections
  proj_mfma<128><<<(N_STAY + 63) / 64, 256, 0, stream>>>(x_stay, fWpS, bp_stay, hs, N_STAY);
  proj_mfma<64><<<(N_PAT + 63) / 64, 256, 0, stream>>>(x_pat, fWpP, bp_pat, hp, N_PAT);

  const int AGG_S = (N_STAY * 64 + 255) / 256;
  const int AGG_P = (N_PAT * 64 + 255) / 256;

  for (int l = 0; l < 2; ++l) {
    ushort_t* fWl0 = fWlB + (size_t)(l * 3 + 0) * 8192;
    ushort_t* fWl1 = fWlB + (size_t)(l * 3 + 1) * 8192;
    ushort_t* fWl2 = fWlB + (size_t)(l * 3 + 2) * 8192;
    ushort_t* fWr0 = fWrB + (size_t)(l * 3 + 0) * 8192;
    ushort_t* fWr1 = fWrB + (size_t)(l * 3 + 1) * 8192;
    ushort_t* fWr2 = fWrB + (size_t)(l * 3 + 2) * 8192;
    const float* bl0 = bl + (size_t)(l * 3 + 0) * H;
    const float* bl1 = bl + (size_t)(l * 3 + 1) * H;
    const float* bl2 = bl + (size_t)(l * 3 + 2) * H;
    const float* g  = ln_g + (size_t)l * H;
    const float* bb = ln_b + (size_t)l * H;

    agg_kernel<<<AGG_P, 256, 0, stream>>>(hs, off1, csr1, agg1, N_PAT);
    agg_kernel<<<AGG_S, 256, 0, stream>>>(hp, off2, csr2, agg2, N_STAY);
    agg_kernel<<<AGG_S, 256, 0, stream>>>(hs, off3, csr3, agg3, N_STAY);

    sage_pat_mfma<<<(N_PAT + 63) / 64, 256, 0, stream>>>(
        agg1, hp, fWl0, fWr0, bl0, g, bb, hp, N_PAT);
    sage_stay_mfma<<<(N_STAY + 63) / 64, 256, 0, stream>>>(
        agg2, agg3, hs, fWl1, fWr1, fWl2, fWr2, bl1, bl2, g, bb, hs, N_STAY);
  }

  reg_kernel<<<(N_STAY + 3) / 4, 256, 0, stream>>>(hs, Wreg, breg, out, N_STAY);
}